// Round 6
// baseline (305.953 us; speedup 1.0000x reference)
//
#include <hip/hip_runtime.h>

// out[s,:] = mask[s] ? source[C(s),:] : inputs[s,:], C(s) = #masked rows < s.
// prep: row-level mask decode + prefix count -> rowsrc[s] (C(s) or -1).
// gather: PERSISTENT blocks (2048 = 8/CU, zero churn), 4 consecutive rows
// per block, uniform rowsrc loads hoisted, explicit 2-row software pipeline
// (8 float4 loads in flight), nontemporal stores.

typedef float f4 __attribute__((ext_vector_type(4)));

#define S_ROWS 8192
#define D4 1024                        // float4 per row (D=4096)
#define PREP_THREADS 256
#define ROWS_PER_THREAD (S_ROWS / PREP_THREADS)  // 32
#define GATHER_THREADS 256
#define ROWS_PER_BLK 4
#define GATHER_BLOCKS (S_ROWS / ROWS_PER_BLK)    // 2048 = 8 per CU

// Single-block: detect mask storage layout, prefix-count masked rows,
// emit rowsrc[s] = C(s) if masked else -1.
__global__ __launch_bounds__(PREP_THREADS) void prep_kernel(
    const void* __restrict__ mask_raw, int* __restrict__ rowsrc) {
  __shared__ int s_not01, s_notF;
  __shared__ int sums[PREP_THREADS];
  __shared__ int excl[PREP_THREADS];
  const int t = threadIdx.x;
  if (t == 0) { s_not01 = 0; s_notF = 0; }
  __syncthreads();

  // Layout detection over first S_ROWS bytes (valid in every layout):
  //   int32 -> words all 0/1; float32 -> words all 0/0x3F800000; else bytes.
  const unsigned int* w = (const unsigned int*)mask_raw;
  int not01 = 0, notF = 0;
  for (int i = t; i < S_ROWS / 4; i += PREP_THREADS) {
    const unsigned int v = w[i];
    not01 |= (v > 1u) ? 1 : 0;
    notF  |= (v != 0u && v != 0x3F800000u) ? 1 : 0;
  }
  if (not01) atomicOr(&s_not01, 1);
  if (notF)  atomicOr(&s_notF, 1);
  __syncthreads();
  const int mode = (!s_not01) ? 0 : ((!s_notF) ? 1 : 2);  // 0=i32, 1=f32, 2=u8

  int vals[ROWS_PER_THREAD];
  const int base = t * ROWS_PER_THREAD;
  int local = 0;
  for (int k = 0; k < ROWS_PER_THREAD; ++k) {
    const int s = base + k;
    int mv;
    if (mode == 0)      mv = (((const int*)mask_raw)[s] != 0);
    else if (mode == 1) mv = (((const float*)mask_raw)[s] != 0.0f);
    else                mv = (((const unsigned char*)mask_raw)[s] != 0);
    vals[k] = mv;
    local += mv;
  }
  sums[t] = local;
  __syncthreads();
  if (t == 0) {  // serial 256-entry exclusive scan — trivial
    int acc = 0;
    for (int i = 0; i < PREP_THREADS; ++i) { excl[i] = acc; acc += sums[i]; }
  }
  __syncthreads();
  int run = excl[t];
  for (int k = 0; k < ROWS_PER_THREAD; ++k) {
    const int s = base + k;
    rowsrc[s] = vals[k] ? run : -1;
    run += vals[k];
  }
}

// Persistent gather: 4 rows/block. Row sources resolved up-front (uniform ->
// scalar loads), then a 2-row rotating pipeline: load row j+1 while storing
// row j. 8 independent 16B loads in flight at steady state per thread.
__global__ __launch_bounds__(GATHER_THREADS) void gather_kernel(
    const f4* __restrict__ in, const f4* __restrict__ src,
    const int* __restrict__ rowsrc, f4* __restrict__ out) {
  const int t = threadIdx.x;
  const int s0 = blockIdx.x * ROWS_PER_BLK;

  const f4* p[ROWS_PER_BLK];
#pragma unroll
  for (int j = 0; j < ROWS_PER_BLK; ++j) {
    const int r = rowsrc[s0 + j];  // wave-uniform -> s_load
    p[j] = (r >= 0) ? (src + (size_t)r * D4) : (in + (size_t)(s0 + j) * D4);
  }
  f4* __restrict__ o = out + (size_t)s0 * D4;

  f4 a0, a1, a2, a3, b0, b1, b2, b3;

#define LD_A(j) { const f4* pj = p[j]; \
    a0 = pj[t]; a1 = pj[t + 256]; a2 = pj[t + 512]; a3 = pj[t + 768]; }
#define LD_B(j) { const f4* pj = p[j]; \
    b0 = pj[t]; b1 = pj[t + 256]; b2 = pj[t + 512]; b3 = pj[t + 768]; }
#define ST_A(j) { f4* oj = o + (size_t)(j) * D4; \
    __builtin_nontemporal_store(a0, oj + t); \
    __builtin_nontemporal_store(a1, oj + t + 256); \
    __builtin_nontemporal_store(a2, oj + t + 512); \
    __builtin_nontemporal_store(a3, oj + t + 768); }
#define ST_B(j) { f4* oj = o + (size_t)(j) * D4; \
    __builtin_nontemporal_store(b0, oj + t); \
    __builtin_nontemporal_store(b1, oj + t + 256); \
    __builtin_nontemporal_store(b2, oj + t + 512); \
    __builtin_nontemporal_store(b3, oj + t + 768); }

  LD_A(0)
  LD_B(1)
  ST_A(0)
  LD_A(2)
  ST_B(1)
  LD_B(3)
  ST_A(2)
  ST_B(3)

#undef LD_A
#undef LD_B
#undef ST_A
#undef ST_B
}

extern "C" void kernel_launch(void* const* d_in, const int* in_sizes, int n_in,
                              void* d_out, int out_size, void* d_ws, size_t ws_size,
                              hipStream_t stream) {
  const f4* inputs = (const f4*)d_in[0];
  const void* mask = d_in[1];
  const f4* source = (const f4*)d_in[2];
  f4* out = (f4*)d_out;
  int* rowsrc = (int*)d_ws;  // 8192 ints = 32 KiB scratch

  prep_kernel<<<1, PREP_THREADS, 0, stream>>>(mask, rowsrc);
  gather_kernel<<<GATHER_BLOCKS, GATHER_THREADS, 0, stream>>>(
      inputs, source, rowsrc, out);
}